// Round 6
// baseline (288.644 us; speedup 1.0000x reference)
//
#include <hip/hip_runtime.h>

// FeatureAggregation, round 6: 4-launch pipeline.
//   k_pre  : zt transpose + query build + WcT/Mt (MFMA, straight from f32 weights) + bu + b_eff
//   k_mid  : gemmU (32x256 tiles, K 4-staged) + passA (16B gather loads, f16 LDS), 6 blocks/CU
//   k_main : per-q: key tile -> MFMA scores (split-K) -> softmax -> MFMA g
//   k_final: out[:,256:768] = G @ Mt^T + b_eff (32x128 tiles, 256 blocks); out[:,0:256] = q_z
//
// key index fact (reference's raw reshape):
//   key[q,k,j<256] = bilinear(Z[q>>3], r[256*(q&7) + 4k + (j>>6), j&63])
//   key[q,k,256+m] = r[q,k,:] . w1[m,:] + b1[m]
// algebra:
//   U = query @ Wc + bu, Wc[i][h*512+j] = sum_d Wq[h*64+d][i] * 0.125*Wk[h*64+d][j]
//   out = G @ Mt^T + b_eff, g[q][h*512+j] = sum_k attn[q,h,k]*key[q,k,j]
//   Mt[e][h*512+j] = sum_d Wo[e][h*64+d] * Wv[h*64+d][j]

typedef _Float16 half8 __attribute__((ext_vector_type(8)));
typedef _Float16 half4v __attribute__((ext_vector_type(4)));
typedef float f32x4 __attribute__((ext_vector_type(4)));

// ---------------- ws element offsets (f16 units) ----------------
#define O_QRY   1048576u    // 2048*512
#define O_WCT   2097152u    // [4096][512]
#define O_MT    4194304u    // [512][4096]
#define O_U     6291456u    // 2048*4096
#define O_G     14680064u   // 2048*4096
#define O_ZT    23068672u   // 256*256*256
#define O_ZR    39845888u   // 256*2048*64
#define O_F32   73400320u   // f32 region (bu 4096, b_eff 512)

// ---------------- k_pre ----------------
// blocks: [0,2048) zt | [2048,3072) query | [3072,3584) WcT | [3584,4096) Mt
//         [4096,4112) bu | [4112,4240) b_eff
__global__ __launch_bounds__(256) void k_pre(
    const float* __restrict__ Z, const float* __restrict__ ipw,
    const float* __restrict__ opw, const float* __restrict__ q_z,
    const float* __restrict__ Qm, const float* __restrict__ w2,
    const float* __restrict__ b2, const float* __restrict__ ipb,
    const float* __restrict__ opb,
    _Float16* __restrict__ wsh, float* __restrict__ bu, float* __restrict__ b_eff)
{
    __shared__ __align__(16) unsigned char sbuf[33792];
    int b = blockIdx.x, t = threadIdx.x;

    if (b < 2048) {
        // ---- zt: Z[c][x][y] f32 -> Zt[x][y][c] f16, y-tile 32 ----
        float (*sT)[33] = (float(*)[33])sbuf;
        int x = b >> 3, yt = (b & 7) * 32;
#pragma unroll
        for (int i = 0; i < 8; ++i) {
            int g = i * 256 + t;
            int c = g >> 3, y = (g & 7) * 4;
            float4 v = *(const float4*)(Z + (size_t)c * 65536 + x * 256 + yt + y);
            sT[c][y] = v.x; sT[c][y + 1] = v.y; sT[c][y + 2] = v.z; sT[c][y + 3] = v.w;
        }
        __syncthreads();
        _Float16* Zt = wsh + O_ZT;
        int c4 = (t & 63) * 4;
#pragma unroll
        for (int i = 0; i < 8; ++i) {
            int y = (t >> 6) * 8 + i;
            half4v o;
#pragma unroll
            for (int j = 0; j < 4; ++j) o[j] = (_Float16)sT[c4 + j][y];
            *(half4v*)(Zt + ((size_t)(x * 256 + yt + y)) * 256 + c4) = o;
        }
    } else if (b < 3072) {
        // ---- query build, 4 elems/thread ----
        int e4 = ((b - 2048) * 256 + t) * 4;
        int q = e4 >> 9, j = e4 & 511;
        half4v o;
        if (j < 256) {
            float4 v = *(const float4*)(q_z + q * 256 + j);
            o[0] = (_Float16)v.x; o[1] = (_Float16)v.y;
            o[2] = (_Float16)v.z; o[3] = (_Float16)v.w;
        } else {
            float q0 = Qm[q * 3], q1 = Qm[q * 3 + 1], q2 = Qm[q * 3 + 2];
#pragma unroll
            for (int u = 0; u < 4; ++u) {
                int m = j - 256 + u;
                o[u] = (_Float16)(q0 * w2[m * 3] + q1 * w2[m * 3 + 1] + q2 * w2[m * 3 + 2] + b2[m]);
            }
        }
        *(half4v*)(wsh + O_QRY + e4) = o;
    } else if (b < 4096) {
        // ---- WcT / Mt 64x64 output tiles via MFMA, K=64 per head ----
        int isMt = (b >= 3584);
        int b2 = b - (isMt ? 3584 : 3072);
        int h = b2 >> 6, jt = (b2 >> 3) & 7, lt = b2 & 7;   // lt: i-tile (WcT) or e-tile (Mt)
        _Float16 (*sAm)[72] = (_Float16(*)[72])sbuf;         // A: m-major [m][d]
        _Float16 (*sBn)[72] = (_Float16(*)[72])(sbuf + 9216);// B: n-major [n][d]
        int j0 = jt * 64, l0 = lt * 64;
        int dd = t >> 4, c4 = (t & 15) * 4;
#pragma unroll
        for (int ii = 0; ii < 4; ++ii) {
            int d = ii * 16 + dd;
            if (!isMt) {
                // WcT: m=j (from Wk, transposed, *0.125), n=i (from Wq, transposed)
                float4 k4 = *(const float4*)(ipw + (size_t)(512 + h * 64 + d) * 512 + j0 + c4);
                float4 q4 = *(const float4*)(ipw + (size_t)(h * 64 + d) * 512 + l0 + c4);
                sAm[c4 + 0][d] = (_Float16)(0.125f * k4.x);
                sAm[c4 + 1][d] = (_Float16)(0.125f * k4.y);
                sAm[c4 + 2][d] = (_Float16)(0.125f * k4.z);
                sAm[c4 + 3][d] = (_Float16)(0.125f * k4.w);
                sBn[c4 + 0][d] = (_Float16)q4.x;
                sBn[c4 + 1][d] = (_Float16)q4.y;
                sBn[c4 + 2][d] = (_Float16)q4.z;
                sBn[c4 + 3][d] = (_Float16)q4.w;
            } else {
                // Mt: m=e (from Wo rows, direct), n=j (from Wv, transposed)
                int e = ii * 16 + dd;
                float4 o4 = *(const float4*)(opw + (size_t)(l0 + e) * 512 + h * 64 + c4);
                half4v ov;
                ov[0] = (_Float16)o4.x; ov[1] = (_Float16)o4.y;
                ov[2] = (_Float16)o4.z; ov[3] = (_Float16)o4.w;
                *(half4v*)&sAm[e][c4] = ov;
                float4 v4 = *(const float4*)(ipw + (size_t)(1024 + h * 64 + d) * 512 + j0 + c4);
                sBn[c4 + 0][d] = (_Float16)v4.x;
                sBn[c4 + 1][d] = (_Float16)v4.y;
                sBn[c4 + 2][d] = (_Float16)v4.z;
                sBn[c4 + 3][d] = (_Float16)v4.w;
            }
        }
        __syncthreads();
        int w = t >> 6, l = t & 63;
        int arow = l & 15, kg = (l >> 4) << 3;
        f32x4 acc[4] = {};
#pragma unroll
        for (int kk = 0; kk < 64; kk += 32) {
            half8 a = *(const half8*)&sAm[w * 16 + arow][kk + kg];
#pragma unroll
            for (int nt = 0; nt < 4; ++nt) {
                half8 bb = *(const half8*)&sBn[nt * 16 + arow][kk + kg];
                acc[nt] = __builtin_amdgcn_mfma_f32_16x16x32_f16(a, bb, acc[nt], 0, 0, 0);
            }
        }
        int rg = (l >> 4) << 2;
        if (!isMt) {
            _Float16* Wc = wsh + O_WCT;
#pragma unroll
            for (int nt = 0; nt < 4; ++nt)
#pragma unroll
                for (int v = 0; v < 4; ++v)
                    Wc[(size_t)(h * 512 + j0 + w * 16 + rg + v) * 512 + l0 + nt * 16 + arow] =
                        (_Float16)acc[nt][v];
        } else {
            _Float16* Mt = wsh + O_MT;
#pragma unroll
            for (int nt = 0; nt < 4; ++nt)
#pragma unroll
                for (int v = 0; v < 4; ++v)
                    Mt[(size_t)(l0 + w * 16 + rg + v) * 4096 + h * 512 + j0 + nt * 16 + arow] =
                        (_Float16)acc[nt][v];
        }
    } else if (b < 4112) {
        // ---- bu[c] ----
        int c = (b - 4096) * 256 + t;
        int h = c >> 9, j = c & 511;
        float s = 0.f;
#pragma unroll 4
        for (int d = 0; d < 64; ++d)
            s += ipb[512 + (h << 6) + d] * ipw[(size_t)(512 + (h << 6) + d) * 512 + j];
        bu[c] = 0.125f * s;
    } else {
        // ---- b_eff: one wave per output e ----
        int e = (b - 4112) * 4 + (t >> 6), l = t & 63;
        const float* worow = opw + (size_t)e * 512;
        float s = 0.f;
#pragma unroll
        for (int i = 0; i < 8; ++i)
            s += ipb[1024 + l + 64 * i] * worow[l + 64 * i];
#pragma unroll
        for (int mm = 1; mm < 64; mm <<= 1) s += __shfl_xor(s, mm, 64);
        if (l == 0) b_eff[e] = s + opb[e];
    }
}

// ---- k_mid: gemmU (blocks [0,1024)) + passA (blocks [1024,5120)) ----
__global__ __launch_bounds__(256, 6) void k_mid(
    const float* __restrict__ r, _Float16* __restrict__ wsh,
    const float* __restrict__ bu)
{
    __shared__ __align__(16) unsigned char smem[16896];
    int b = blockIdx.x, t = threadIdx.x, w = t >> 6, l = t & 63;

    if (b < 1024) {
        // ---- gemmU: U = query @ WcT^T + bu, 32x256 tile, K in 4 stages of 128 ----
        _Float16 (*sA)[136] = (_Float16(*)[136])smem;
        const _Float16* A = wsh + O_QRY;
        const _Float16* B = wsh + O_WCT;
        _Float16* U = wsh + O_U;
        int q0 = (b & 63) * 32;
        int colb = (b >> 6) * 256 + w * 64;
        f32x4 acc[2][4] = {};
        int arow = l & 15, kg = (l >> 4) << 3;
#pragma unroll
        for (int s = 0; s < 4; ++s) {
#pragma unroll
            for (int i = 0; i < 2; ++i) {
                int e = i * 2048 + t * 8;
                *(half8*)&sA[e >> 7][e & 127] =
                    *(const half8*)(A + (size_t)(q0 + (e >> 7)) * 512 + s * 128 + (e & 127));
            }
            __syncthreads();
#pragma unroll
            for (int kk = 0; kk < 128; kk += 32) {
                half8 a[2], bb[4];
#pragma unroll
                for (int mt = 0; mt < 2; ++mt) a[mt] = *(const half8*)&sA[mt * 16 + arow][kk + kg];
#pragma unroll
                for (int nt = 0; nt < 4; ++nt)
                    bb[nt] = *(const half8*)(B + (size_t)(colb + nt * 16 + arow) * 512 + s * 128 + kk + kg);
#pragma unroll
                for (int mt = 0; mt < 2; ++mt)
#pragma unroll
                    for (int nt = 0; nt < 4; ++nt)
                        acc[mt][nt] = __builtin_amdgcn_mfma_f32_16x16x32_f16(a[mt], bb[nt], acc[mt][nt], 0, 0, 0);
            }
            __syncthreads();
        }
#pragma unroll
        for (int mt = 0; mt < 2; ++mt)
#pragma unroll
            for (int nt = 0; nt < 4; ++nt)
#pragma unroll
                for (int v = 0; v < 4; ++v) {
                    int row = q0 + mt * 16 + ((l >> 4) << 2) + v;
                    int col = colb + nt * 16 + arow;
                    U[(size_t)row * 4096 + col] = (_Float16)(acc[mt][nt][v] + bu[col]);
                }
    } else {
        // ---- passA: bilinear interp, 16B channel loads -> Zr[ch][point] ----
        _Float16 (*sT)[264] = (_Float16(*)[264])smem;   // [pt][ch]
        const _Float16* Zt = wsh + O_ZT;
        _Float16* Zr = wsh + O_ZR;
        int pb = b - 1024;
        const float2* r2 = (const float2*)r;
        int hb = l >> 5, ch0 = (l & 31) * 8;
#pragma unroll
        for (int i = 0; i < 4; ++i) {
            int ptl = i * 8 + w * 2 + hb;
            float2 rv = r2[pb * 32 + ptl];
            int x1 = (int)rv.x, y1 = (int)rv.y;
            float dx = rv.x - (float)x1, dy = rv.y - (float)y1;
            float w11 = (1.f - dx) * (1.f - dy), w21 = dx * (1.f - dy);
            float w12 = (1.f - dx) * dy,         w22 = dx * dy;
            const _Float16* base = Zt + ((size_t)(x1 * 256 + y1)) * 256 + ch0;
            half8 z11 = *(const half8*)(base);
            half8 z12 = *(const half8*)(base + 256);
            half8 z21 = *(const half8*)(base + 65536);
            half8 z22 = *(const half8*)(base + 65536 + 256);
            half8 o;
#pragma unroll
            for (int c = 0; c < 8; ++c)
                o[c] = (_Float16)(w11 * (float)z11[c] + w21 * (float)z21[c]
                                + w12 * (float)z12[c] + w22 * (float)z22[c]);
            *(half8*)&sT[ptl][ch0] = o;
        }
        __syncthreads();
        int ch_ = t >> 2, pt8 = (t & 3) * 8;
#pragma unroll
        for (int g = 0; g < 4; ++g) {
            int ch = g * 64 + ch_;
            half8 o;
#pragma unroll
            for (int j = 0; j < 8; ++j) o[j] = sT[pt8 + j][ch];
            *(half8*)(Zr + (size_t)ch * 131072 + pb * 32 + pt8) = o;
        }
    }
}

// ---------------- main: key tile -> MFMA scores (split-K) -> softmax -> MFMA g ----------------
__global__ __launch_bounds__(512, 2) void k_main(
    const _Float16* __restrict__ Zr, const float* __restrict__ r,
    const float* __restrict__ w1, const float* __restrict__ b1,
    const _Float16* __restrict__ U, _Float16* __restrict__ G)
{
    __shared__ __align__(16) _Float16 sKey[64][520];
    __shared__ __align__(16) _Float16 sU[8][520];     // u[q]; reused as sG after scores
    __shared__ float sP[512];
    __shared__ float sP2[512];
    __shared__ __align__(16) _Float16 sA16[16][72];   // attn in A-fragment layout

    int q = blockIdx.x;
    int t = threadIdx.x, w = t >> 6, l = t & 63;
    int ch = q >> 3, s8 = q & 7;

    for (int i = t; i < 576; i += 512) ((unsigned*)sA16)[i] = 0u;

    const _Float16* src = Zr + ((size_t)ch * 2048 + s8 * 256) * 64;
#pragma unroll
    for (int i = 0; i < 4; ++i) {
        int e = i * 4096 + t * 8;
        *(half8*)&sKey[e >> 8][e & 255] = *(const half8*)(src + e);
    }
    {
        int e = t * 8;
        *(half8*)&sU[e >> 9][e & 511] = *(const half8*)(U + (size_t)q * 4096 + e);
    }
    {
        int m = t & 255, half = t >> 8;
        float w10 = w1[2 * m], w11 = w1[2 * m + 1], b1m = b1[m];
        const float2* r2q = (const float2*)r + (size_t)q * 64;
#pragma unroll 8
        for (int i = 0; i < 32; ++i) {
            int k = half * 32 + i;
            float2 rv = r2q[k];
            sKey[k][256 + m] = (_Float16)(rv.x * w10 + rv.y * w11 + b1m);
        }
    }
    __syncthreads();

    // scores via MFMA, split-K
    {
        f32x4 acc = {};
        int arow = l & 15, kg = (l >> 4) << 3;
        int wm = w & 3, khalf = (w >> 2) << 8;
        const _Float16* ar = &sKey[wm * 16 + arow][khalf + kg];
        const _Float16* br = &sU[l & 7][khalf + kg];
#pragma unroll
        for (int kk = 0; kk < 256; kk += 32)
            acc = __builtin_amdgcn_mfma_f32_16x16x32_f16(
                *(const half8*)(ar + kk), *(const half8*)(br + kk), acc, 0, 0, 0);
        if ((l & 15) < 8) {
            int h = l & 15, krow0 = wm * 16 + ((l >> 4) << 2);
            float* dst = (w < 4) ? sP : sP2;
#pragma unroll
            for (int v = 0; v < 4; ++v) dst[(h << 6) + krow0 + v] = acc[v];
        }
    }
    __syncthreads();

    // softmax per head (wave == head)
    {
        float v = sP[t] + sP2[t];
        float mx = v;
#pragma unroll
        for (int mm = 1; mm < 64; mm <<= 1) mx = fmaxf(mx, __shfl_xor(mx, mm, 64));
        float e = __expf(v - mx);
        float sm = e;
#pragma unroll
        for (int mm = 1; mm < 64; mm <<= 1) sm += __shfl_xor(sm, mm, 64);
        sA16[w][l] = (_Float16)(e / sm);
    }
    __syncthreads();

    // g = attn @ key via MFMA; wave w covers cols [w*64, w*64+64)
    {
        f32x4 acc[4] = {};
        int arow = l & 15, kq = (l >> 4) << 3;
        half8 a0 = *(const half8*)&sA16[arow][kq];
        half8 a1 = *(const half8*)&sA16[arow][32 + kq];
#pragma unroll
        for (int nt = 0; nt < 4; ++nt) {
            int n0 = (w << 6) + (nt << 4);
            half8 b0, b1f;
#pragma unroll
            for (int jj = 0; jj < 8; ++jj) b0[jj] = sKey[kq + jj][n0 + arow];
            acc[nt] = __builtin_amdgcn_mfma_f32_16x16x32_f16(a0, b0, acc[nt], 0, 0, 0);
#pragma unroll
            for (int jj = 0; jj < 8; ++jj) b1f[jj] = sKey[32 + kq + jj][n0 + arow];
            acc[nt] = __builtin_amdgcn_mfma_f32_16x16x32_f16(a1, b1f, acc[nt], 0, 0, 0);
        }
        if (l < 32) {
            int rgrp = (l >> 4) << 2;
#pragma unroll
            for (int nt = 0; nt < 4; ++nt) {
                int n0 = (w << 6) + (nt << 4);
#pragma unroll
                for (int v = 0; v < 4; ++v)
                    sU[rgrp + v][n0 + arow] = (_Float16)acc[nt][v];
            }
        }
    }
    __syncthreads();

    {
        int c = t * 8;
        *(half8*)(G + (size_t)q * 4096 + c) = *(const half8*)&sU[c >> 9][c & 511];
    }
}

// ---------------- final: 32x128 tiles, grid (64,4) ----------------
__global__ __launch_bounds__(256) void k_final(
    const _Float16* __restrict__ G, const _Float16* __restrict__ Mt,
    const float* __restrict__ b_eff, const float* __restrict__ qz,
    float* __restrict__ out)
{
    __shared__ __align__(16) _Float16 sA[32][520];
    int rb = blockIdx.x, cb = blockIdx.y;
    int q0 = rb * 32;
    int t = threadIdx.x, w = t >> 6, l = t & 63;

    if (cb == 0) {
#pragma unroll
        for (int i = 0; i < 8; ++i) {
            int idx4 = i * 256 + t;
            int row = idx4 >> 6, c = (idx4 & 63) << 2;
            *(float4*)&out[(size_t)(q0 + row) * 768 + c] =
                *(const float4*)&qz[(size_t)(q0 + row) * 256 + c];
        }
    }

    f32x4 acc[2][2] = {};
    int arow = l & 15, kg = (l >> 4) << 3;
    int e0 = cb * 128 + (w << 5);
    for (int c = 0; c < 8; ++c) {
#pragma unroll
        for (int i = 0; i < 8; ++i) {
            int e = i * 2048 + t * 8;
            *(half8*)&sA[e >> 9][e & 511] =
                *(const half8*)(G + (size_t)(q0 + (e >> 9)) * 4096 + c * 512 + (e & 511));
        }
        __syncthreads();
#pragma unroll 4
        for (int kk = 0; kk < 512; kk += 32) {
            half8 a[2], bb[2];
#pragma unroll
            for (int nt = 0; nt < 2; ++nt)
                bb[nt] = *(const half8*)(Mt + (size_t)(e0 + nt * 16 + arow) * 4096 + c * 512 + kk + kg);
#pragma unroll
            for (int mt = 0; mt < 2; ++mt) {
                a[mt] = *(const half8*)&sA[mt * 16 + arow][kk + kg];
#pragma unroll
                for (int nt = 0; nt < 2; ++nt)
                    acc[mt][nt] = __builtin_amdgcn_mfma_f32_16x16x32_f16(a[mt], bb[nt], acc[mt][nt], 0, 0, 0);
            }
        }
        __syncthreads();
    }
#pragma unroll
    for (int mt = 0; mt < 2; ++mt)
#pragma unroll
        for (int nt = 0; nt < 2; ++nt)
#pragma unroll
            for (int v = 0; v < 4; ++v) {
                int row = q0 + mt * 16 + ((l >> 4) << 2) + v;
                int ecol = e0 + nt * 16 + arow;
                out[(size_t)row * 768 + 256 + ecol] = acc[mt][nt][v] + b_eff[ecol];
            }
}

extern "C" void kernel_launch(void* const* d_in, const int* in_sizes, int n_in,
                              void* d_out, int out_size, void* d_ws, size_t ws_size,
                              hipStream_t stream) {
    const float* Z          = (const float*)d_in[0];
    const float* Qm         = (const float*)d_in[1];
    const float* q_z        = (const float*)d_in[2];
    const float* r          = (const float*)d_in[3];
    const float* w1         = (const float*)d_in[4];
    const float* b1         = (const float*)d_in[5];
    const float* w2         = (const float*)d_in[6];
    const float* b2         = (const float*)d_in[7];
    const float* in_proj_w  = (const float*)d_in[8];
    const float* in_proj_b  = (const float*)d_in[9];
    const float* out_proj_w = (const float*)d_in[10];
    const float* out_proj_b = (const float*)d_in[11];
    float* out = (float*)d_out;

    _Float16* wsh = (_Float16*)d_ws;
    _Float16* Mt    = wsh + O_MT;
    _Float16* U     = wsh + O_U;
    _Float16* G     = wsh + O_G;
    _Float16* Zr    = wsh + O_ZR;
    float*    bu    = (float*)(wsh + O_F32);
    float*    b_eff = bu + 4096;

    k_pre<<<4240, 256, 0, stream>>>(Z, in_proj_w, out_proj_w, q_z, Qm, w2, b2,
                                    in_proj_b, out_proj_b, wsh, bu, b_eff);
    k_mid<<<5120, 256, 0, stream>>>(r, wsh, bu);
    k_main<<<2048, 512, 0, stream>>>(Zr, r, w1, b1, U, G);
    k_final<<<dim3(64, 4), 256, 0, stream>>>(G, Mt, b_eff, q_z, out);
}

// Round 7
// 271.934 us; speedup vs baseline: 1.0614x; 1.0614x over previous
//
#include <hip/hip_runtime.h>

// FeatureAggregation, round 7: revert k_mid to R5 (R6 f16-LDS passA was a
// 4-way-conflict regression), keep R6 k_pre/k_final, add XOR group swizzle
// to k_main's sKey to kill g-phase B-fragment bank conflicts.
// Pipeline:
//   k_pre  : zt transpose + query build + WcT/Mt (MFMA from f32 weights) + bu + b_eff
//   k_mid  : gemmU (64x256, K-split-2) + passA (dword gather, f32 LDS) [R5 version]
//   k_main : per-q: key tile (swizzled) -> MFMA scores -> softmax -> MFMA g
//   k_final: out[:,256:768] = G @ Mt^T + b_eff (32x128 tiles); out[:,0:256] = q_z
//
// key index fact (reference's raw reshape):
//   key[q,k,j<256] = bilinear(Z[q>>3], r[256*(q&7) + 4k + (j>>6), j&63])
//   key[q,k,256+m] = r[q,k,:] . w1[m,:] + b1[m]
// sKey swizzle: element (k,j) lives at column ((j>>3) ^ ((k>>3)&7))*8 + (j&7).

typedef _Float16 half8 __attribute__((ext_vector_type(8)));
typedef _Float16 half4v __attribute__((ext_vector_type(4)));
typedef _Float16 half2v __attribute__((ext_vector_type(2)));
typedef float f32x4 __attribute__((ext_vector_type(4)));

// ---------------- ws element offsets (f16 units) ----------------
#define O_QRY   1048576u    // 2048*512
#define O_WCT   2097152u    // [4096][512]
#define O_MT    4194304u    // [512][4096]
#define O_U     6291456u    // 2048*4096
#define O_G     14680064u   // 2048*4096
#define O_ZT    23068672u   // 256*256*256
#define O_ZR    39845888u   // 256*2048*64
#define O_F32   73400320u   // f32 region (bu 4096, b_eff 512)

// ---------------- k_pre ----------------
// blocks: [0,2048) zt | [2048,3072) query | [3072,3584) WcT | [3584,4096) Mt
//         [4096,4112) bu | [4112,4240) b_eff
__global__ __launch_bounds__(256) void k_pre(
    const float* __restrict__ Z, const float* __restrict__ ipw,
    const float* __restrict__ opw, const float* __restrict__ q_z,
    const float* __restrict__ Qm, const float* __restrict__ w2,
    const float* __restrict__ b2, const float* __restrict__ ipb,
    const float* __restrict__ opb,
    _Float16* __restrict__ wsh, float* __restrict__ bu, float* __restrict__ b_eff)
{
    __shared__ __align__(16) unsigned char sbuf[33792];
    int b = blockIdx.x, t = threadIdx.x;

    if (b < 2048) {
        // ---- zt: Z[c][x][y] f32 -> Zt[x][y][c] f16, y-tile 32 ----
        float (*sT)[33] = (float(*)[33])sbuf;
        int x = b >> 3, yt = (b & 7) * 32;
#pragma unroll
        for (int i = 0; i < 8; ++i) {
            int g = i * 256 + t;
            int c = g >> 3, y = (g & 7) * 4;
            float4 v = *(const float4*)(Z + (size_t)c * 65536 + x * 256 + yt + y);
            sT[c][y] = v.x; sT[c][y + 1] = v.y; sT[c][y + 2] = v.z; sT[c][y + 3] = v.w;
        }
        __syncthreads();
        _Float16* Zt = wsh + O_ZT;
        int c4 = (t & 63) * 4;
#pragma unroll
        for (int i = 0; i < 8; ++i) {
            int y = (t >> 6) * 8 + i;
            half4v o;
#pragma unroll
            for (int j = 0; j < 4; ++j) o[j] = (_Float16)sT[c4 + j][y];
            *(half4v*)(Zt + ((size_t)(x * 256 + yt + y)) * 256 + c4) = o;
        }
    } else if (b < 3072) {
        // ---- query build, 4 elems/thread ----
        int e4 = ((b - 2048) * 256 + t) * 4;
        int q = e4 >> 9, j = e4 & 511;
        half4v o;
        if (j < 256) {
            float4 v = *(const float4*)(q_z + q * 256 + j);
            o[0] = (_Float16)v.x; o[1] = (_Float16)v.y;
            o[2] = (_Float16)v.z; o[3] = (_Float16)v.w;
        } else {
            float q0 = Qm[q * 3], q1 = Qm[q * 3 + 1], q2 = Qm[q * 3 + 2];
#pragma unroll
            for (int u = 0; u < 4; ++u) {
                int m = j - 256 + u;
                o[u] = (_Float16)(q0 * w2[m * 3] + q1 * w2[m * 3 + 1] + q2 * w2[m * 3 + 2] + b2[m]);
            }
        }
        *(half4v*)(wsh + O_QRY + e4) = o;
    } else if (b < 4096) {
        // ---- WcT / Mt 64x64 output tiles via MFMA, K=64 per head ----
        int isMt = (b >= 3584);
        int b2_ = b - (isMt ? 3584 : 3072);
        int h = b2_ >> 6, jt = (b2_ >> 3) & 7, lt = b2_ & 7;
        _Float16 (*sAm)[72] = (_Float16(*)[72])sbuf;
        _Float16 (*sBn)[72] = (_Float16(*)[72])(sbuf + 9216);
        int j0 = jt * 64, l0 = lt * 64;
        int dd = t >> 4, c4 = (t & 15) * 4;
#pragma unroll
        for (int ii = 0; ii < 4; ++ii) {
            int d = ii * 16 + dd;
            if (!isMt) {
                float4 k4 = *(const float4*)(ipw + (size_t)(512 + h * 64 + d) * 512 + j0 + c4);
                float4 q4 = *(const float4*)(ipw + (size_t)(h * 64 + d) * 512 + l0 + c4);
                sAm[c4 + 0][d] = (_Float16)(0.125f * k4.x);
                sAm[c4 + 1][d] = (_Float16)(0.125f * k4.y);
                sAm[c4 + 2][d] = (_Float16)(0.125f * k4.z);
                sAm[c4 + 3][d] = (_Float16)(0.125f * k4.w);
                sBn[c4 + 0][d] = (_Float16)q4.x;
                sBn[c4 + 1][d] = (_Float16)q4.y;
                sBn[c4 + 2][d] = (_Float16)q4.z;
                sBn[c4 + 3][d] = (_Float16)q4.w;
            } else {
                int e = ii * 16 + dd;
                float4 o4 = *(const float4*)(opw + (size_t)(l0 + e) * 512 + h * 64 + c4);
                half4v ov;
                ov[0] = (_Float16)o4.x; ov[1] = (_Float16)o4.y;
                ov[2] = (_Float16)o4.z; ov[3] = (_Float16)o4.w;
                *(half4v*)&sAm[e][c4] = ov;
                float4 v4 = *(const float4*)(ipw + (size_t)(1024 + h * 64 + d) * 512 + j0 + c4);
                sBn[c4 + 0][d] = (_Float16)v4.x;
                sBn[c4 + 1][d] = (_Float16)v4.y;
                sBn[c4 + 2][d] = (_Float16)v4.z;
                sBn[c4 + 3][d] = (_Float16)v4.w;
            }
        }
        __syncthreads();
        int w = t >> 6, l = t & 63;
        int arow = l & 15, kg = (l >> 4) << 3;
        f32x4 acc[4] = {};
#pragma unroll
        for (int kk = 0; kk < 64; kk += 32) {
            half8 a = *(const half8*)&sAm[w * 16 + arow][kk + kg];
#pragma unroll
            for (int nt = 0; nt < 4; ++nt) {
                half8 bb = *(const half8*)&sBn[nt * 16 + arow][kk + kg];
                acc[nt] = __builtin_amdgcn_mfma_f32_16x16x32_f16(a, bb, acc[nt], 0, 0, 0);
            }
        }
        int rg = (l >> 4) << 2;
        if (!isMt) {
            _Float16* Wc = wsh + O_WCT;
#pragma unroll
            for (int nt = 0; nt < 4; ++nt)
#pragma unroll
                for (int v = 0; v < 4; ++v)
                    Wc[(size_t)(h * 512 + j0 + w * 16 + rg + v) * 512 + l0 + nt * 16 + arow] =
                        (_Float16)acc[nt][v];
        } else {
            _Float16* Mt = wsh + O_MT;
#pragma unroll
            for (int nt = 0; nt < 4; ++nt)
#pragma unroll
                for (int v = 0; v < 4; ++v)
                    Mt[(size_t)(l0 + w * 16 + rg + v) * 4096 + h * 512 + j0 + nt * 16 + arow] =
                        (_Float16)acc[nt][v];
        }
    } else if (b < 4112) {
        // ---- bu[c] ----
        int c = (b - 4096) * 256 + t;
        int h = c >> 9, j = c & 511;
        float s = 0.f;
#pragma unroll 4
        for (int d = 0; d < 64; ++d)
            s += ipb[512 + (h << 6) + d] * ipw[(size_t)(512 + (h << 6) + d) * 512 + j];
        bu[c] = 0.125f * s;
    } else {
        // ---- b_eff: one wave per output e ----
        int e = (b - 4112) * 4 + (t >> 6), l = t & 63;
        const float* worow = opw + (size_t)e * 512;
        float s = 0.f;
#pragma unroll
        for (int i = 0; i < 8; ++i)
            s += ipb[1024 + l + 64 * i] * worow[l + 64 * i];
#pragma unroll
        for (int mm = 1; mm < 64; mm <<= 1) s += __shfl_xor(s, mm, 64);
        if (l == 0) b_eff[e] = s + opb[e];
    }
}

// ---- k_mid (R5 version): gemmU (blocks [0,512)) + passA (blocks [512,4608)) ----
__global__ __launch_bounds__(256, 4) void k_mid(
    const float* __restrict__ r, _Float16* __restrict__ wsh,
    const float* __restrict__ bu)
{
    __shared__ __align__(16) unsigned char smem[33792];
    int b = blockIdx.x, t = threadIdx.x, w = t >> 6, l = t & 63;

    if (b < 512) {
        // ---- gemmU: U = query @ WcT^T + bu, 64x256 out tile, K split in 2 LDS stages ----
        _Float16 (*sA)[264] = (_Float16(*)[264])smem;
        const _Float16* A = wsh + O_QRY;
        const _Float16* B = wsh + O_WCT;
        _Float16* U = wsh + O_U;
        int q0 = (b & 31) * 64;
        int colb = (b >> 5) * 256 + w * 64;
        f32x4 acc[4][4] = {};
        int arow = l & 15, kg = (l >> 4) << 3;
#pragma unroll
        for (int half = 0; half < 2; ++half) {
#pragma unroll
            for (int i = 0; i < 8; ++i) {
                int e = i * 2048 + t * 8;
                *(half8*)&sA[e >> 8][e & 255] =
                    *(const half8*)(A + (size_t)(q0 + (e >> 8)) * 512 + half * 256 + (e & 255));
            }
            __syncthreads();
#pragma unroll 2
            for (int kk = 0; kk < 256; kk += 32) {
                half8 a[4], bb[4];
#pragma unroll
                for (int mt = 0; mt < 4; ++mt) a[mt] = *(const half8*)&sA[mt * 16 + arow][kk + kg];
#pragma unroll
                for (int nt = 0; nt < 4; ++nt)
                    bb[nt] = *(const half8*)(B + (size_t)(colb + nt * 16 + arow) * 512 + half * 256 + kk + kg);
#pragma unroll
                for (int mt = 0; mt < 4; ++mt)
#pragma unroll
                    for (int nt = 0; nt < 4; ++nt)
                        acc[mt][nt] = __builtin_amdgcn_mfma_f32_16x16x32_f16(a[mt], bb[nt], acc[mt][nt], 0, 0, 0);
            }
            __syncthreads();
        }
#pragma unroll
        for (int mt = 0; mt < 4; ++mt)
#pragma unroll
            for (int nt = 0; nt < 4; ++nt)
#pragma unroll
                for (int v = 0; v < 4; ++v) {
                    int row = q0 + mt * 16 + ((l >> 4) << 2) + v;
                    int col = colb + nt * 16 + arow;
                    U[(size_t)row * 4096 + col] = (_Float16)(acc[mt][nt][v] + bu[col]);
                }
    } else {
        // ---- passA: bilinear interp, channel-contiguous -> Zr[ch][qp][col] ----
        float (*sT)[33] = (float(*)[33])smem;
        const _Float16* Zt = wsh + O_ZT;
        _Float16* Zr = wsh + O_ZR;
        int pb = b - 512;
        const float2* r2 = (const float2*)r;
#pragma unroll 2
        for (int i = 0; i < 8; ++i) {
            int ptl = w * 8 + i;
            float2 rv = r2[pb * 32 + ptl];
            int x1 = (int)rv.x, y1 = (int)rv.y;
            float dx = rv.x - (float)x1, dy = rv.y - (float)y1;
            float w11 = (1.f - dx) * (1.f - dy), w21 = dx * (1.f - dy);
            float w12 = (1.f - dx) * dy,         w22 = dx * dy;
            const _Float16* base = Zt + ((size_t)(x1 * 256 + y1)) * 256;
#pragma unroll
            for (int cg = 0; cg < 2; ++cg) {
                int c = cg * 128 + l * 2;
                half2v z11 = *(const half2v*)(base + c);
                half2v z12 = *(const half2v*)(base + 256 + c);
                half2v z21 = *(const half2v*)(base + 65536 + c);
                half2v z22 = *(const half2v*)(base + 65536 + 256 + c);
                sT[c][ptl]     = w11 * (float)z11[0] + w21 * (float)z21[0]
                               + w12 * (float)z12[0] + w22 * (float)z22[0];
                sT[c + 1][ptl] = w11 * (float)z11[1] + w21 * (float)z21[1]
                               + w12 * (float)z12[1] + w22 * (float)z22[1];
            }
        }
        __syncthreads();
        int ch0 = t >> 2, colc = (t & 3) * 8;
#pragma unroll
        for (int g = 0; g < 4; ++g) {
            int ch = g * 64 + ch0;
            half8 o;
#pragma unroll
            for (int j = 0; j < 8; ++j) o[j] = (_Float16)sT[ch][colc + j];
            *(half8*)(Zr + (size_t)ch * 131072 + pb * 32 + colc) = o;
        }
    }
}

// ---------------- main: swizzled key tile -> MFMA scores -> softmax -> MFMA g ----------------
// sKey element (k,j) at column ((j>>3) ^ ((k>>3)&7))*8 + (j&7)
__global__ __launch_bounds__(512, 2) void k_main(
    const _Float16* __restrict__ Zr, const float* __restrict__ r,
    const float* __restrict__ w1, const float* __restrict__ b1,
    const _Float16* __restrict__ U, _Float16* __restrict__ G)
{
    __shared__ __align__(16) _Float16 sKey[64][520];
    __shared__ __align__(16) _Float16 sU[8][520];     // u[q]; reused as sG after scores
    __shared__ float sP[512];
    __shared__ float sP2[512];
    __shared__ __align__(16) _Float16 sA16[16][72];   // attn in A-fragment layout

    int q = blockIdx.x;
    int t = threadIdx.x, w = t >> 6, l = t & 63;
    int ch = q >> 3, s8 = q & 7;

    for (int i = t; i < 576; i += 512) ((unsigned*)sA16)[i] = 0u;

    // Z-part of key: contiguous 32KB, swizzled store
    const _Float16* src = Zr + ((size_t)ch * 2048 + s8 * 256) * 64;
#pragma unroll
    for (int i = 0; i < 4; ++i) {
        int e = i * 4096 + t * 8;
        int k = e >> 8, col = e & 255;
        int colS = (((col >> 3) ^ (k >> 3)) << 3);
        *(half8*)&sKey[k][colS] = *(const half8*)(src + e);
    }
    // u[q]
    {
        int e = t * 8;
        *(half8*)&sU[e >> 9][e & 511] = *(const half8*)(U + (size_t)q * 4096 + e);
    }
    // r_proj (swizzled scalar store)
    {
        int m = t & 255, half = t >> 8;
        float w10 = w1[2 * m], w11 = w1[2 * m + 1], b1m = b1[m];
        const float2* r2q = (const float2*)r + (size_t)q * 64;
#pragma unroll 8
        for (int i = 0; i < 32; ++i) {
            int k = half * 32 + i;
            float2 rv = r2q[k];
            int col = 256 + m;
            int colS = ((((col >> 3) ^ (k >> 3)) << 3)) + (col & 7);
            sKey[k][colS] = (_Float16)(rv.x * w10 + rv.y * w11 + b1m);
        }
    }
    __syncthreads();

    // scores via MFMA, split-K (swizzled A reads)
    {
        f32x4 acc = {};
        int arow = l & 15, kg = (l >> 4) << 3;
        int wm = w & 3, khalf = (w >> 2) << 8;
        int k = wm * 16 + arow;
        int sw = (k >> 3) & 7;
        const _Float16* krow = &sKey[k][0];
        const _Float16* br = &sU[l & 7][khalf + kg];
#pragma unroll
        for (int kk = 0; kk < 256; kk += 32) {
            int col = khalf + kk + kg;
            half8 av = *(const half8*)(krow + ((((col >> 3) ^ sw) << 3)));
            acc = __builtin_amdgcn_mfma_f32_16x16x32_f16(
                av, *(const half8*)(br + kk), acc, 0, 0, 0);
        }
        if ((l & 15) < 8) {
            int h = l & 15, krow0 = wm * 16 + ((l >> 4) << 2);
            float* dst = (w < 4) ? sP : sP2;
#pragma unroll
            for (int v = 0; v < 4; ++v) dst[(h << 6) + krow0 + v] = acc[v];
        }
    }
    __syncthreads();

    // softmax per head (wave == head)
    {
        float v = sP[t] + sP2[t];
        float mx = v;
#pragma unroll
        for (int mm = 1; mm < 64; mm <<= 1) mx = fmaxf(mx, __shfl_xor(mx, mm, 64));
        float e = __expf(v - mx);
        float sm = e;
#pragma unroll
        for (int mm = 1; mm < 64; mm <<= 1) sm += __shfl_xor(sm, mm, 64);
        sA16[w][l] = (_Float16)(e / sm);
    }
    __syncthreads();

    // g = attn @ key via MFMA; wave w covers cols [w*64, w*64+64)
    // B-fragment rows kq+jj spread across banks by the (k>>3) swizzle
    {
        f32x4 acc[4] = {};
        int arow = l & 15, kq = (l >> 4) << 3;
        int sw0 = kq >> 3, sw1 = 4 + (kq >> 3);
        half8 a0 = *(const half8*)&sA16[arow][kq];
        half8 a1 = *(const half8*)&sA16[arow][32 + kq];
#pragma unroll
        for (int nt = 0; nt < 4; ++nt) {
            int n0 = (w << 6) + (nt << 4);
            int colb_ = n0 + arow;
            int cg = colb_ >> 3, co = colb_ & 7;
            int c0 = ((cg ^ sw0) << 3) + co;
            int c1 = ((cg ^ sw1) << 3) + co;
            half8 b0, b1f;
#pragma unroll
            for (int jj = 0; jj < 8; ++jj) b0[jj] = sKey[kq + jj][c0];
            acc[nt] = __builtin_amdgcn_mfma_f32_16x16x32_f16(a0, b0, acc[nt], 0, 0, 0);
#pragma unroll
            for (int jj = 0; jj < 8; ++jj) b1f[jj] = sKey[32 + kq + jj][c1];
            acc[nt] = __builtin_amdgcn_mfma_f32_16x16x32_f16(a1, b1f, acc[nt], 0, 0, 0);
        }
        if (l < 32) {
            int rgrp = (l >> 4) << 2;
#pragma unroll
            for (int nt = 0; nt < 4; ++nt) {
                int n0 = (w << 6) + (nt << 4);
#pragma unroll
                for (int v = 0; v < 4; ++v)
                    sU[rgrp + v][n0 + arow] = (_Float16)acc[nt][v];
            }
        }
    }
    __syncthreads();

    {
        int c = t * 8;
        *(half8*)(G + (size_t)q * 4096 + c) = *(const half8*)&sU[c >> 9][c & 511];
    }
}

// ---------------- final: 32x128 tiles, grid (64,4) ----------------
__global__ __launch_bounds__(256) void k_final(
    const _Float16* __restrict__ G, const _Float16* __restrict__ Mt,
    const float* __restrict__ b_eff, const float* __restrict__ qz,
    float* __restrict__ out)
{
    __shared__ __align__(16) _Float16 sA[32][520];
    int rb = blockIdx.x, cb = blockIdx.y;
    int q0 = rb * 32;
    int t = threadIdx.x, w = t >> 6, l = t & 63;

    if (cb == 0) {
#pragma unroll
        for (int i = 0; i < 8; ++i) {
            int idx4 = i * 256 + t;
            int row = idx4 >> 6, c = (idx4 & 63) << 2;
            *(float4*)&out[(size_t)(q0 + row) * 768 + c] =
                *(const float4*)&qz[(size_t)(q0 + row) * 256 + c];
        }
    }

    f32x4 acc[2][2] = {};
    int arow = l & 15, kg = (l >> 4) << 3;
    int e0 = cb * 128 + (w << 5);
    for (int c = 0; c < 8; ++c) {
#pragma unroll
        for (int i = 0; i < 8; ++i) {
            int e = i * 2048 + t * 8;
            *(half8*)&sA[e >> 9][e & 511] =
                *(const half8*)(G + (size_t)(q0 + (e >> 9)) * 4096 + c * 512 + (e & 511));
        }
        __syncthreads();
#pragma unroll 4
        for (int kk = 0; kk < 512; kk += 32) {
            half8 a[2], bb[2];
#pragma unroll
            for (int nt = 0; nt < 2; ++nt)
                bb[nt] = *(const half8*)(Mt + (size_t)(e0 + nt * 16 + arow) * 4096 + c * 512 + kk + kg);
#pragma unroll
            for (int mt = 0; mt < 2; ++mt) {
                a[mt] = *(const half8*)&sA[mt * 16 + arow][kk + kg];
#pragma unroll
                for (int nt = 0; nt < 2; ++nt)
                    acc[mt][nt] = __builtin_amdgcn_mfma_f32_16x16x32_f16(a[mt], bb[nt], acc[mt][nt], 0, 0, 0);
            }
        }
        __syncthreads();
    }
#pragma unroll
    for (int mt = 0; mt < 2; ++mt)
#pragma unroll
        for (int nt = 0; nt < 2; ++nt)
#pragma unroll
            for (int v = 0; v < 4; ++v) {
                int row = q0 + mt * 16 + ((l >> 4) << 2) + v;
                int ecol = e0 + nt * 16 + arow;
                out[(size_t)row * 768 + 256 + ecol] = acc[mt][nt][v] + b_eff[ecol];
            }
}

extern "C" void kernel_launch(void* const* d_in, const int* in_sizes, int n_in,
                              void* d_out, int out_size, void* d_ws, size_t ws_size,
                              hipStream_t stream) {
    const float* Z          = (const float*)d_in[0];
    const float* Qm         = (const float*)d_in[1];
    const float* q_z        = (const float*)d_in[2];
    const float* r          = (const float*)d_in[3];
    const float* w1         = (const float*)d_in[4];
    const float* b1         = (const float*)d_in[5];
    const float* w2         = (const float*)d_in[6];
    const float* b2         = (const float*)d_in[7];
    const float* in_proj_w  = (const float*)d_in[8];
    const float* in_proj_b  = (const float*)d_in[9];
    const float* out_proj_w = (const float*)d_in[10];
    const float* out_proj_b = (const float*)d_in[11];
    float* out = (float*)d_out;

    _Float16* wsh = (_Float16*)d_ws;
    _Float16* Mt    = wsh + O_MT;
    _Float16* U     = wsh + O_U;
    _Float16* G     = wsh + O_G;
    _Float16* Zr    = wsh + O_ZR;
    float*    bu    = (float*)(wsh + O_F32);
    float*    b_eff = bu + 4096;

    k_pre<<<4240, 256, 0, stream>>>(Z, in_proj_w, out_proj_w, q_z, Qm, w2, b2,
                                    in_proj_b, out_proj_b, wsh, bu, b_eff);
    k_mid<<<4608, 256, 0, stream>>>(r, wsh, bu);
    k_main<<<2048, 512, 0, stream>>>(Zr, r, w1, b1, U, G);
    k_final<<<dim3(64, 4), 256, 0, stream>>>(G, Mt, b_eff, q_z, out);
}